// Round 3
// baseline (522.106 us; speedup 1.0000x reference)
//
#include <hip/hip_runtime.h>
#include <hip/hip_bf16.h>

#define NN 50000
#define NE 800000

typedef __bf16 bf16_t;
typedef bf16_t bf16x8 __attribute__((ext_vector_type(8)));
typedef float f32x4 __attribute__((ext_vector_type(4)));

// fast gelu: x * sigmoid(1.595769x + 0.0713548x^3), max abs err vs erf-gelu ~4e-4
__device__ __forceinline__ float gelu_f(float x) {
    float v = x * fmaf(x * x, 0.07135481627f, 1.595769122f);
    float e = __expf(-v);
    return x * __builtin_amdgcn_rcpf(1.0f + e);
}

// ---------------- weight folding into MFMA B-fragment order ----------------
// idx = ((nt*nkc + (k>>5))*64 + ((k>>3)&3)*16 + lrow)*8 + (k&7), n = nt*16+lrow
__device__ void fold_frag(int K, const float* W, const float* g, const float* b,
                          const float* mu, const float* v, const float* c,
                          bf16_t* Wf, float* cb, int tid, float* part) {
    const int n = tid & 63, kc = tid >> 6;
    const int nt = n >> 4, lrow = n & 15, nkc = K >> 5;
    const int kq = K >> 2, k0 = kc * kq, k1 = k0 + kq;
    float acc = 0.f;
    for (int k = k0; k < k1; ++k) {
        float w = W[k * 64 + n];
        float s = 1.0f, o = 0.0f;
        if (g) {
            s = g[k] * __frsqrt_rn(v[k] + 1e-3f);
            o = b[k] - mu[k] * s;
        }
        int idx = ((nt * nkc + (k >> 5)) * 64 + ((k >> 3) & 3) * 16 + lrow) * 8 + (k & 7);
        Wf[idx] = (bf16_t)(w * s);
        acc += o * w;
    }
    part[kc * 64 + n] = acc;
    __syncthreads();
    if (kc == 0) cb[n] = c[n] + part[n] + part[64 + n] + part[128 + n] + part[192 + n];
}

__global__ void fold_kernel(
    const float* mg1, const float* mb1, const float* mmu1, const float* mv1,
    const float* mW1, const float* mc1,
    const float* mg2, const float* mb2, const float* mmu2, const float* mv2,
    const float* mW2, const float* mc2,
    const float* eW1, const float* ec1, const float* eW2, const float* ec2,
    const float* ug1, const float* ub1, const float* umu1, const float* uv1,
    const float* uW1, const float* uc1,
    const float* ug2, const float* ub2, const float* umu2, const float* uv2,
    const float* uW2, const float* uc2,
    bf16_t* wcat, bf16_t* uW1f, bf16_t* uW2f,
    float* cm1, float* cm2, float* ce1, float* ce2, float* cu1, float* cu2)
{
    __shared__ float part[256];
    int t = threadIdx.x;
    switch (blockIdx.x) {
        case 0: fold_frag(64,  mW1, mg1, mb1, mmu1, mv1, mc1, wcat,         cm1, t, part); break;
        case 1: fold_frag(64,  mW2, mg2, mb2, mmu2, mv2, mc2, wcat + 4096,  cm2, t, part); break;
        case 2: fold_frag(64,  eW1, nullptr, nullptr, nullptr, nullptr, ec1, wcat + 8192,  ce1, t, part); break;
        case 3: fold_frag(64,  eW2, nullptr, nullptr, nullptr, nullptr, ec2, wcat + 12288, ce2, t, part); break;
        case 4: fold_frag(128, uW1, ug1, ub1, umu1, uv1, uc1, uW1f, cu1, t, part); break;
        case 5: fold_frag(64,  uW2, ug2, ub2, umu2, uv2, uc2, uW2f, cu2, t, part); break;
    }
}

// ---------------- CSR build ----------------
__global__ void hist_kernel(const int* __restrict__ src, int* __restrict__ cnt) {
    int e = blockIdx.x * 256 + threadIdx.x;
    if (e < NE) atomicAdd(&cnt[src[e]], 1);
}

__global__ void scanA_kernel(const int* __restrict__ cnt, int* __restrict__ part,
                             int* __restrict__ btot) {
    __shared__ int s[256];
    int tid = threadIdx.x;
    int i = blockIdx.x * 256 + tid;
    int v = (i < NN) ? cnt[i] : 0;
    s[tid] = v;
    __syncthreads();
    #pragma unroll
    for (int off = 1; off < 256; off <<= 1) {
        int t = (tid >= off) ? s[tid - off] : 0;
        __syncthreads();
        s[tid] += t;
        __syncthreads();
    }
    if (i < NN) part[i] = s[tid] - v;
    if (tid == 255) btot[blockIdx.x] = s[255];
}

__global__ void scanB_kernel(int* __restrict__ btot, int nblk) {
    __shared__ int s[256];
    int tid = threadIdx.x;
    int v = (tid < nblk) ? btot[tid] : 0;
    s[tid] = v;
    __syncthreads();
    #pragma unroll
    for (int off = 1; off < 256; off <<= 1) {
        int t = (tid >= off) ? s[tid - off] : 0;
        __syncthreads();
        s[tid] += t;
        __syncthreads();
    }
    if (tid < nblk) btot[tid] = s[tid] - v;
}

__global__ void scanC_kernel(const int* __restrict__ part, const int* __restrict__ btot,
                             int* __restrict__ woff) {
    int i = blockIdx.x * 256 + threadIdx.x;
    if (i < NN) woff[i] = part[i] + btot[i >> 8];
}

// forward map: CSR slot -> edge id
__global__ void fill_kernel(const int* __restrict__ src, int* __restrict__ woff,
                            int* __restrict__ eidx) {
    int e = blockIdx.x * 256 + threadIdx.x;
    if (e < NE) {
        int p = atomicAdd(&woff[src[e]], 1);
        eidx[p] = e;
    }
}

// ---------------- MFMA helpers ----------------
__device__ __forceinline__ void mk_frag_hilo(const float* row, int quad,
        bf16x8& hi0, bf16x8& lo0, bf16x8& hi1, bf16x8& lo1)
{
    #pragma unroll
    for (int j = 0; j < 8; ++j) {
        float x0 = row[quad * 8 + j];
        float x1 = row[32 + quad * 8 + j];
        bf16_t h0 = (bf16_t)x0, h1 = (bf16_t)x1;
        hi0[j] = h0; lo0[j] = (bf16_t)(x0 - (float)h0);
        hi1[j] = h1; lo1[j] = (bf16_t)(x1 - (float)h1);
    }
}

__device__ __forceinline__ bf16x8 ldb(const bf16_t* wf, int slot, int lane) {
    return *(const bf16x8*)(wf + (slot * 64 + lane) * 8);
}

__device__ __forceinline__ void gemm64_hilo(const bf16_t* wf, int m,
        bf16x8 h0, bf16x8 l0, bf16x8 h1, bf16x8 l1, f32x4 (&acc)[4], int lane)
{
    #pragma unroll
    for (int nt = 0; nt < 4; ++nt) {
        bf16x8 b0 = ldb(wf, m * 8 + nt * 2 + 0, lane);
        bf16x8 b1 = ldb(wf, m * 8 + nt * 2 + 1, lane);
        f32x4 c = {0.f, 0.f, 0.f, 0.f};
        c = __builtin_amdgcn_mfma_f32_16x16x32_bf16(h0, b0, c, 0, 0, 0);
        c = __builtin_amdgcn_mfma_f32_16x16x32_bf16(l0, b0, c, 0, 0, 0);
        c = __builtin_amdgcn_mfma_f32_16x16x32_bf16(h1, b1, c, 0, 0, 0);
        c = __builtin_amdgcn_mfma_f32_16x16x32_bf16(l1, b1, c, 0, 0, 0);
        acc[nt] = c;
    }
}

__device__ __forceinline__ void gemm64(const bf16_t* wf, int m,
        bf16x8 a0, bf16x8 a1, f32x4 (&acc)[4], int lane)
{
    #pragma unroll
    for (int nt = 0; nt < 4; ++nt) {
        bf16x8 b0 = ldb(wf, m * 8 + nt * 2 + 0, lane);
        bf16x8 b1 = ldb(wf, m * 8 + nt * 2 + 1, lane);
        f32x4 c = {0.f, 0.f, 0.f, 0.f};
        c = __builtin_amdgcn_mfma_f32_16x16x32_bf16(a0, b0, c, 0, 0, 0);
        c = __builtin_amdgcn_mfma_f32_16x16x32_bf16(a1, b1, c, 0, 0, 0);
        acc[nt] = c;
    }
}

// gelu -> per-wave A-fragment-order buffer
__device__ __forceinline__ void epi_to_frag(const f32x4 (&acc)[4], const float* bias,
        bf16_t* h, int lrow, int quad)
{
    #pragma unroll
    for (int nt = 0; nt < 4; ++nt) {
        float bb = bias[nt * 16 + lrow];
        #pragma unroll
        for (int r = 0; r < 4; ++r)
            h[((nt * 2 + (lrow >> 3)) * 16 + quad * 4 + r) * 8 + (lrow & 7)] =
                (bf16_t)gelu_f(acc[nt][r] + bb);
    }
}

// ---------------- per-node message MLP ----------------
__global__ __launch_bounds__(256) void node_msg_kernel(
    const float* __restrict__ node_feats, const bf16_t* __restrict__ wcat,
    const float* __restrict__ cm1, const float* __restrict__ cm2,
    bf16_t* __restrict__ msg)
{
    __shared__ bf16_t wf[8192];      // mW1f, mW2f (16 KB)
    __shared__ bf16_t hf[4][1024];

    const int tid  = threadIdx.x;
    const int wave = tid >> 6;
    const int lane = tid & 63;
    const int quad = lane >> 4;
    const int lrow = lane & 15;

    #pragma unroll
    for (int i = 0; i < 4; ++i) {
        int chunk = tid + i * 256;
        *(bf16x8*)(wf + chunk * 8) = *(const bf16x8*)(wcat + chunk * 8);
    }
    __syncthreads();

    const int nbase = blockIdx.x * 64 + wave * 16;
    int arow = nbase + lrow;
    arow = arow < NN ? arow : NN - 1;

    f32x4 acc[4];
    {
        const float* nrow = node_feats + (size_t)arow * 64;
        bf16x8 h0, l0, h1, l1;
        mk_frag_hilo(nrow, quad, h0, l0, h1, l1);
        gemm64_hilo(wf, 0, h0, l0, h1, l1, acc, lane);
        epi_to_frag(acc, cm1, hf[wave], lrow, quad);
    }
    bf16x8 a0 = *(const bf16x8*)(hf[wave] + lane * 8);
    bf16x8 a1 = *(const bf16x8*)(hf[wave] + (lane + 64) * 8);
    gemm64(wf, 1, a0, a1, acc, lane);

    #pragma unroll
    for (int nt = 0; nt < 4; ++nt) {
        float bb = cm2[nt * 16 + lrow];
        #pragma unroll
        for (int r = 0; r < 4; ++r) {
            int row = nbase + quad * 4 + r;
            if (row < NN)
                msg[(size_t)row * 64 + nt * 16 + lrow] = (bf16_t)gelu_f(acc[nt][r] + bb);
        }
    }
}

// ---------------- edge kernel: CSR-ordered er MLP + gate + segmented atomic reduce ----------------
// Wave handles 16 consecutive CSR slots (sorted by src node) -> ~2 segments/wave ->
// coalesced 64-float atomic row flush per segment. No buf round-trip, no agg kernel.
__global__ __launch_bounds__(256) void edge_kernel(
    const float* __restrict__ edge_feats,
    const int* __restrict__ src, const int* __restrict__ dst,
    const int* __restrict__ eidx,
    const bf16_t* __restrict__ wcat,
    const float* __restrict__ ce1, const float* __restrict__ ce2,
    const bf16_t* __restrict__ msg,
    float* __restrict__ s_acc)
{
    __shared__ bf16_t wf[8192];      // eW1f, eW2f (16 KB)
    __shared__ bf16_t hf[4][1024];   // hidden fragments
    __shared__ bf16_t sme[4][1024];  // per-wave 16 edges x 64 cols (XOR-swizzled)
    __shared__ int    nds[4][16];    // per-wave src node of each slot

    const int tid  = threadIdx.x;
    const int wave = tid >> 6;
    const int lane = tid & 63;
    const int quad = lane >> 4;
    const int lrow = lane & 15;

    #pragma unroll
    for (int i = 0; i < 4; ++i) {
        int chunk = tid + i * 256;
        *(bf16x8*)(wf + chunk * 8) = *(const bf16x8*)(wcat + 8192 + chunk * 8);
    }
    __syncthreads();

    const int sbase = blockIdx.x * 64 + wave * 16;
    bf16_t* h  = hf[wave];
    bf16_t* sm = sme[wave];
    int*    nd = nds[wave];

    // edge id for this lane's slot-row (replicated across quads; L1 broadcast)
    int e_lrow = eidx[sbase + lrow];
    if (lane < 16) nd[lane] = src[e_lrow];    // lanes 0..15 have lrow == lane

    const int r0 = lane >> 3;        // slot rows 0..7 / 8..15 for the msg gather
    const int c0 = lane & 7;         // 16B chunk within a row
    const int r1 = 8 + r0;
    const int b0 = r0 * 64 + ((c0 * 8) ^ (((r0 >> 2) & 3) << 4));
    const int b1 = r1 * 64 + ((c0 * 8) ^ (((r1 >> 2) & 3) << 4));

    // msg-row gathers (coalesced 16B, 8 lanes per row), issued early
    int eA = __shfl(e_lrow, r0);
    int eB = __shfl(e_lrow, r1);
    int dA = dst[eA];
    int dB = dst[eB];
    bf16x8 mA = *(const bf16x8*)(msg + (size_t)dA * 64 + c0 * 8);
    bf16x8 mB = *(const bf16x8*)(msg + (size_t)dB * 64 + c0 * 8);

    // er MLP layer 1 on gathered edge_feats row (hides gather latency)
    f32x4 acc[4];
    {
        const float* efr = edge_feats + (size_t)e_lrow * 64;
        bf16x8 h0_, l0_, h1_, l1_;
        mk_frag_hilo(efr, quad, h0_, l0_, h1_, l1_);
        gemm64_hilo(wf, 0, h0_, l0_, h1_, l1_, acc, lane);
        epi_to_frag(acc, ce1, h, lrow, quad);
    }

    // stage gathered msg rows into wave-private LDS (swizzled)
    *(bf16x8*)(sm + b0) = mA;
    *(bf16x8*)(sm + b1) = mB;
    __builtin_amdgcn_wave_barrier();

    // er MLP layer 2
    bf16x8 a0 = *(const bf16x8*)(h + lane * 8);
    bf16x8 a1 = *(const bf16x8*)(h + (lane + 64) * 8);
    gemm64(wf, 1, a0, a1, acc, lane);
    __builtin_amdgcn_wave_barrier();

    // gate in place: cell (slot e=quad*4+r, col=nt*16+lrow)
    #pragma unroll
    for (int nt = 0; nt < 4; ++nt) {
        float bb = ce2[nt * 16 + lrow];
        #pragma unroll
        for (int r = 0; r < 4; ++r) {
            int e = quad * 4 + r;
            int ci = e * 64 + ((nt * 16 + lrow) ^ (((e >> 2) & 3) << 4));
            float er = gelu_f(acc[nt][r] + bb);
            sm[ci] = (bf16_t)(er * (float)sm[ci]);
        }
    }
    __builtin_amdgcn_wave_barrier();

    // segmented reduction over the 16 sorted slots; lane owns column c=lane
    float run = 0.f;
    int cur = nd[0];
    #pragma unroll
    for (int s = 0; s < 16; ++s) {
        int n_s = nd[s];
        if (n_s != cur) {                      // uniform branch (nd same across lanes)
            unsafeAtomicAdd(&s_acc[(size_t)cur * 64 + lane], run);
            run = 0.f; cur = n_s;
        }
        run += (float)sm[s * 64 + (lane ^ (((s >> 2) & 3) << 4))];
    }
    unsafeAtomicAdd(&s_acc[(size_t)cur * 64 + lane], run);
}

// ---------------- update MLP (mean via cnt divide) ----------------
__global__ __launch_bounds__(256) void update_kernel(
    const float* __restrict__ node_feats,
    const float* __restrict__ aggv, const int* __restrict__ cnt,
    const bf16_t* __restrict__ uW1f, const float* __restrict__ cu1,
    const bf16_t* __restrict__ uW2f, const float* __restrict__ cu2,
    float* __restrict__ out)
{
    __shared__ bf16_t w1f[8192];
    __shared__ bf16_t w2f[4096];
    __shared__ bf16_t hf[4][1024];

    const int tid  = threadIdx.x;
    const int wave = tid >> 6;
    const int lane = tid & 63;
    const int quad = lane >> 4;
    const int lrow = lane & 15;

    #pragma unroll
    for (int i = 0; i < 4; ++i) {
        int chunk = tid + i * 256;
        *(bf16x8*)(w1f + chunk * 8) = *(const bf16x8*)(uW1f + chunk * 8);
    }
    #pragma unroll
    for (int i = 0; i < 2; ++i) {
        int chunk = tid + i * 256;
        *(bf16x8*)(w2f + chunk * 8) = *(const bf16x8*)(uW2f + chunk * 8);
    }
    __syncthreads();

    const int nbase = blockIdx.x * 64 + wave * 16;
    int arow = nbase + lrow;
    arow = arow < NN ? arow : NN - 1;

    const float* nf   = node_feats + (size_t)arow * 64;
    const float* srow = aggv + (size_t)arow * 64;
    float inv = 1.0f / fmaxf((float)cnt[arow], 1.0f);

    bf16x8 ah[4], al[4];
    #pragma unroll
    for (int j = 0; j < 8; ++j) {
        float x0 = nf[quad * 8 + j];
        float x1 = nf[32 + quad * 8 + j];
        float x2 = srow[quad * 8 + j] * inv;
        float x3 = srow[32 + quad * 8 + j] * inv;
        bf16_t h0 = (bf16_t)x0, h1 = (bf16_t)x1, h2 = (bf16_t)x2, h3 = (bf16_t)x3;
        ah[0][j] = h0; al[0][j] = (bf16_t)(x0 - (float)h0);
        ah[1][j] = h1; al[1][j] = (bf16_t)(x1 - (float)h1);
        ah[2][j] = h2; al[2][j] = (bf16_t)(x2 - (float)h2);
        ah[3][j] = h3; al[3][j] = (bf16_t)(x3 - (float)h3);
    }

    f32x4 acc[4];
    #pragma unroll
    for (int nt = 0; nt < 4; ++nt) {
        f32x4 c = {0.f, 0.f, 0.f, 0.f};
        #pragma unroll
        for (int kk = 0; kk < 4; ++kk) {
            bf16x8 b = *(const bf16x8*)(w1f + ((nt * 4 + kk) * 64 + lane) * 8);
            c = __builtin_amdgcn_mfma_f32_16x16x32_bf16(ah[kk], b, c, 0, 0, 0);
            c = __builtin_amdgcn_mfma_f32_16x16x32_bf16(al[kk], b, c, 0, 0, 0);
        }
        acc[nt] = c;
    }
    bf16_t* hb = hf[wave];
    epi_to_frag(acc, cu1, hb, lrow, quad);

    bf16x8 ha0 = *(const bf16x8*)(hb + lane * 8);
    bf16x8 ha1 = *(const bf16x8*)(hb + (lane + 64) * 8);
    gemm64(w2f, 0, ha0, ha1, acc, lane);

    #pragma unroll
    for (int nt = 0; nt < 4; ++nt) {
        int col = nt * 16 + lrow;
        float bb = cu2[col];
        #pragma unroll
        for (int r = 0; r < 4; ++r) {
            int row = nbase + quad * 4 + r;
            if (row < NN)
                out[(size_t)row * 64 + col] = gelu_f(acc[nt][r] + bb);
        }
    }
}

// ---------------- launch ----------------
extern "C" void kernel_launch(void* const* d_in, const int* in_sizes, int n_in,
                              void* d_out, int out_size, void* d_ws, size_t ws_size,
                              hipStream_t stream) {
    const float* node_feats = (const float*)d_in[0];
    const float* edge_feats = (const float*)d_in[1];
    const int*   src        = (const int*)d_in[2];
    const int*   dst        = (const int*)d_in[3];

    char* ws = (char*)d_ws;
    size_t off = 0;
    float* s_acc = (float*)(ws + off);  off += (size_t)NN * 256;   // 12.8 MB (zeroed)
    int*   cnt   = (int*)(ws + off);    off += (size_t)NN * 4;     // zeroed with s_acc
    int*   woff  = (int*)(ws + off);    off += (size_t)NN * 4;
    int*   part  = (int*)(ws + off);    off += (size_t)NN * 4;
    int*   btot  = (int*)(ws + off);    off += 1024;
    int*   eidx  = (int*)(ws + off);    off += (size_t)NE * 4;     // 3.2 MB
    bf16_t* msg  = (bf16_t*)(ws + off); off += (size_t)NN * 128;   // 6.4 MB
    bf16_t* wcat = (bf16_t*)(ws + off); off += 32768;
    bf16_t* uW1f = (bf16_t*)(ws + off); off += 16384;
    bf16_t* uW2f = (bf16_t*)(ws + off); off += 8192;
    float* cm1 = (float*)(ws + off); off += 256;
    float* cm2 = (float*)(ws + off); off += 256;
    float* ce1 = (float*)(ws + off); off += 256;
    float* ce2 = (float*)(ws + off); off += 256;
    float* cu1 = (float*)(ws + off); off += 256;
    float* cu2 = (float*)(ws + off); off += 256;

    hipMemsetAsync(s_acc, 0, (size_t)NN * 256 + (size_t)NN * 4, stream);

    fold_kernel<<<6, 256, 0, stream>>>(
        (const float*)d_in[4],  (const float*)d_in[5],  (const float*)d_in[6],  (const float*)d_in[7],
        (const float*)d_in[8],  (const float*)d_in[9],
        (const float*)d_in[10], (const float*)d_in[11], (const float*)d_in[12], (const float*)d_in[13],
        (const float*)d_in[14], (const float*)d_in[15],
        (const float*)d_in[16], (const float*)d_in[17], (const float*)d_in[18], (const float*)d_in[19],
        (const float*)d_in[20], (const float*)d_in[21], (const float*)d_in[22], (const float*)d_in[23],
        (const float*)d_in[24], (const float*)d_in[25],
        (const float*)d_in[26], (const float*)d_in[27], (const float*)d_in[28], (const float*)d_in[29],
        (const float*)d_in[30], (const float*)d_in[31],
        wcat, uW1f, uW2f, cm1, cm2, ce1, ce2, cu1, cu2);

    node_msg_kernel<<<(NN + 63) / 64, 256, 0, stream>>>(node_feats, wcat, cm1, cm2, msg);

    hist_kernel<<<(NE + 255) / 256, 256, 0, stream>>>(src, cnt);

    const int NBLK = (NN + 255) / 256;   // 196
    scanA_kernel<<<NBLK, 256, 0, stream>>>(cnt, part, btot);
    scanB_kernel<<<1, 256, 0, stream>>>(btot, NBLK);
    scanC_kernel<<<NBLK, 256, 0, stream>>>(part, btot, woff);
    fill_kernel<<<(NE + 255) / 256, 256, 0, stream>>>(src, woff, eidx);

    edge_kernel<<<NE / 64, 256, 0, stream>>>(
        edge_feats, src, dst, eidx, wcat, ce1, ce2, msg, s_acc);

    update_kernel<<<(NN + 63) / 64, 256, 0, stream>>>(
        node_feats, s_acc, cnt, uW1f, cu1, uW2f, cu2, (float*)d_out);
}

// Round 4
// 482.946 us; speedup vs baseline: 1.0811x; 1.0811x over previous
//
#include <hip/hip_runtime.h>
#include <hip/hip_bf16.h>

#define NN 50000
#define NE 800000

typedef __bf16 bf16_t;
typedef bf16_t bf16x8 __attribute__((ext_vector_type(8)));
typedef float f32x4 __attribute__((ext_vector_type(4)));

// fast gelu: x * sigmoid(1.595769x + 0.0713548x^3), max abs err vs erf-gelu ~4e-4
__device__ __forceinline__ float gelu_f(float x) {
    float v = x * fmaf(x * x, 0.07135481627f, 1.595769122f);
    float e = __expf(-v);
    return x * __builtin_amdgcn_rcpf(1.0f + e);
}

// ---------------- weight folding into MFMA B-fragment order ----------------
// idx = ((nt*nkc + (k>>5))*64 + ((k>>3)&3)*16 + lrow)*8 + (k&7), n = nt*16+lrow
__device__ void fold_frag(int K, const float* W, const float* g, const float* b,
                          const float* mu, const float* v, const float* c,
                          bf16_t* Wf, float* cb, int tid, float* part) {
    const int n = tid & 63, kc = tid >> 6;
    const int nt = n >> 4, lrow = n & 15, nkc = K >> 5;
    const int kq = K >> 2, k0 = kc * kq, k1 = k0 + kq;
    float acc = 0.f;
    for (int k = k0; k < k1; ++k) {
        float w = W[k * 64 + n];
        float s = 1.0f, o = 0.0f;
        if (g) {
            s = g[k] * __frsqrt_rn(v[k] + 1e-3f);
            o = b[k] - mu[k] * s;
        }
        int idx = ((nt * nkc + (k >> 5)) * 64 + ((k >> 3) & 3) * 16 + lrow) * 8 + (k & 7);
        Wf[idx] = (bf16_t)(w * s);
        acc += o * w;
    }
    part[kc * 64 + n] = acc;
    __syncthreads();
    if (kc == 0) cb[n] = c[n] + part[n] + part[64 + n] + part[128 + n] + part[192 + n];
}

__global__ void fold_kernel(
    const float* mg1, const float* mb1, const float* mmu1, const float* mv1,
    const float* mW1, const float* mc1,
    const float* mg2, const float* mb2, const float* mmu2, const float* mv2,
    const float* mW2, const float* mc2,
    const float* eW1, const float* ec1, const float* eW2, const float* ec2,
    const float* ug1, const float* ub1, const float* umu1, const float* uv1,
    const float* uW1, const float* uc1,
    const float* ug2, const float* ub2, const float* umu2, const float* uv2,
    const float* uW2, const float* uc2,
    bf16_t* wcat, bf16_t* uW1f, bf16_t* uW2f,
    float* cm1, float* cm2, float* ce1, float* ce2, float* cu1, float* cu2)
{
    __shared__ float part[256];
    int t = threadIdx.x;
    switch (blockIdx.x) {
        case 0: fold_frag(64,  mW1, mg1, mb1, mmu1, mv1, mc1, wcat,         cm1, t, part); break;
        case 1: fold_frag(64,  mW2, mg2, mb2, mmu2, mv2, mc2, wcat + 4096,  cm2, t, part); break;
        case 2: fold_frag(64,  eW1, nullptr, nullptr, nullptr, nullptr, ec1, wcat + 8192,  ce1, t, part); break;
        case 3: fold_frag(64,  eW2, nullptr, nullptr, nullptr, nullptr, ec2, wcat + 12288, ce2, t, part); break;
        case 4: fold_frag(128, uW1, ug1, ub1, umu1, uv1, uc1, uW1f, cu1, t, part); break;
        case 5: fold_frag(64,  uW2, ug2, ub2, umu2, uv2, uc2, uW2f, cu2, t, part); break;
    }
}

// ---------------- CSR build ----------------
__global__ void hist_kernel(const int* __restrict__ src, int* __restrict__ cnt) {
    int e = blockIdx.x * 256 + threadIdx.x;
    if (e < NE) atomicAdd(&cnt[src[e]], 1);
}

__global__ void scanA_kernel(const int* __restrict__ cnt, int* __restrict__ part,
                             int* __restrict__ btot) {
    __shared__ int s[256];
    int tid = threadIdx.x;
    int i = blockIdx.x * 256 + tid;
    int v = (i < NN) ? cnt[i] : 0;
    s[tid] = v;
    __syncthreads();
    #pragma unroll
    for (int off = 1; off < 256; off <<= 1) {
        int t = (tid >= off) ? s[tid - off] : 0;
        __syncthreads();
        s[tid] += t;
        __syncthreads();
    }
    if (i < NN) part[i] = s[tid] - v;
    if (tid == 255) btot[blockIdx.x] = s[255];
}

__global__ void scanB_kernel(int* __restrict__ btot, int nblk) {
    __shared__ int s[256];
    int tid = threadIdx.x;
    int v = (tid < nblk) ? btot[tid] : 0;
    s[tid] = v;
    __syncthreads();
    #pragma unroll
    for (int off = 1; off < 256; off <<= 1) {
        int t = (tid >= off) ? s[tid - off] : 0;
        __syncthreads();
        s[tid] += t;
        __syncthreads();
    }
    if (tid < nblk) btot[tid] = s[tid] - v;
}

__global__ void scanC_kernel(const int* __restrict__ part, const int* __restrict__ btot,
                             int* __restrict__ woff) {
    int i = blockIdx.x * 256 + threadIdx.x;
    if (i < NN) woff[i] = part[i] + btot[i >> 8];
}

// ---------------- MFMA helpers ----------------
__device__ __forceinline__ void mk_frag_hilo(const float* row, int quad,
        bf16x8& hi0, bf16x8& lo0, bf16x8& hi1, bf16x8& lo1)
{
    #pragma unroll
    for (int j = 0; j < 8; ++j) {
        float x0 = row[quad * 8 + j];
        float x1 = row[32 + quad * 8 + j];
        bf16_t h0 = (bf16_t)x0, h1 = (bf16_t)x1;
        hi0[j] = h0; lo0[j] = (bf16_t)(x0 - (float)h0);
        hi1[j] = h1; lo1[j] = (bf16_t)(x1 - (float)h1);
    }
}

__device__ __forceinline__ bf16x8 ldb(const bf16_t* wf, int slot, int lane) {
    return *(const bf16x8*)(wf + (slot * 64 + lane) * 8);
}

__device__ __forceinline__ void gemm64_hilo(const bf16_t* wf, int m,
        bf16x8 h0, bf16x8 l0, bf16x8 h1, bf16x8 l1, f32x4 (&acc)[4], int lane)
{
    #pragma unroll
    for (int nt = 0; nt < 4; ++nt) {
        bf16x8 b0 = ldb(wf, m * 8 + nt * 2 + 0, lane);
        bf16x8 b1 = ldb(wf, m * 8 + nt * 2 + 1, lane);
        f32x4 c = {0.f, 0.f, 0.f, 0.f};
        c = __builtin_amdgcn_mfma_f32_16x16x32_bf16(h0, b0, c, 0, 0, 0);
        c = __builtin_amdgcn_mfma_f32_16x16x32_bf16(l0, b0, c, 0, 0, 0);
        c = __builtin_amdgcn_mfma_f32_16x16x32_bf16(h1, b1, c, 0, 0, 0);
        c = __builtin_amdgcn_mfma_f32_16x16x32_bf16(l1, b1, c, 0, 0, 0);
        acc[nt] = c;
    }
}

__device__ __forceinline__ void gemm64(const bf16_t* wf, int m,
        bf16x8 a0, bf16x8 a1, f32x4 (&acc)[4], int lane)
{
    #pragma unroll
    for (int nt = 0; nt < 4; ++nt) {
        bf16x8 b0 = ldb(wf, m * 8 + nt * 2 + 0, lane);
        bf16x8 b1 = ldb(wf, m * 8 + nt * 2 + 1, lane);
        f32x4 c = {0.f, 0.f, 0.f, 0.f};
        c = __builtin_amdgcn_mfma_f32_16x16x32_bf16(a0, b0, c, 0, 0, 0);
        c = __builtin_amdgcn_mfma_f32_16x16x32_bf16(a1, b1, c, 0, 0, 0);
        acc[nt] = c;
    }
}

// gelu -> per-wave A-fragment-order buffer
__device__ __forceinline__ void epi_to_frag(const f32x4 (&acc)[4], const float* bias,
        bf16_t* h, int lrow, int quad)
{
    #pragma unroll
    for (int nt = 0; nt < 4; ++nt) {
        float bb = bias[nt * 16 + lrow];
        #pragma unroll
        for (int r = 0; r < 4; ++r)
            h[((nt * 2 + (lrow >> 3)) * 16 + quad * 4 + r) * 8 + (lrow & 7)] =
                (bf16_t)gelu_f(acc[nt][r] + bb);
    }
}

// ---------------- per-node message MLP ----------------
__global__ __launch_bounds__(256) void node_msg_kernel(
    const float* __restrict__ node_feats, const bf16_t* __restrict__ wcat,
    const float* __restrict__ cm1, const float* __restrict__ cm2,
    bf16_t* __restrict__ msg)
{
    __shared__ bf16_t wf[8192];      // mW1f, mW2f (16 KB)
    __shared__ bf16_t hf[4][1024];

    const int tid  = threadIdx.x;
    const int wave = tid >> 6;
    const int lane = tid & 63;
    const int quad = lane >> 4;
    const int lrow = lane & 15;

    #pragma unroll
    for (int i = 0; i < 4; ++i) {
        int chunk = tid + i * 256;
        *(bf16x8*)(wf + chunk * 8) = *(const bf16x8*)(wcat + chunk * 8);
    }
    __syncthreads();

    const int nbase = blockIdx.x * 64 + wave * 16;
    int arow = nbase + lrow;
    arow = arow < NN ? arow : NN - 1;

    f32x4 acc[4];
    {
        const float* nrow = node_feats + (size_t)arow * 64;
        bf16x8 h0, l0, h1, l1;
        mk_frag_hilo(nrow, quad, h0, l0, h1, l1);
        gemm64_hilo(wf, 0, h0, l0, h1, l1, acc, lane);
        epi_to_frag(acc, cm1, hf[wave], lrow, quad);
    }
    bf16x8 a0 = *(const bf16x8*)(hf[wave] + lane * 8);
    bf16x8 a1 = *(const bf16x8*)(hf[wave] + (lane + 64) * 8);
    gemm64(wf, 1, a0, a1, acc, lane);

    #pragma unroll
    for (int nt = 0; nt < 4; ++nt) {
        float bb = cm2[nt * 16 + lrow];
        #pragma unroll
        for (int r = 0; r < 4; ++r) {
            int row = nbase + quad * 4 + r;
            if (row < NN)
                msg[(size_t)row * 64 + nt * 16 + lrow] = (bf16_t)gelu_f(acc[nt][r] + bb);
        }
    }
}

// ---------------- edge kernel: er MLP + LDS-staged gather/gate + CSR scatter ----------------
// Coalesced edge_feats read (natural order); random access is applied only to the
// SMALLEST tensor (gated bf16 rows scattered to buf). hf time-multiplexed as the
// msg tile: a0/a1 are in registers before the overwrite (wave-lockstep ds order).
// LDS 24.6 KB -> 6 blocks/CU (was 33.3 KB -> 4).
__global__ __launch_bounds__(256) void edge_kernel(
    const float* __restrict__ edge_feats,
    const int* __restrict__ src, const int* __restrict__ dst,
    const bf16_t* __restrict__ wcat,
    const float* __restrict__ ce1, const float* __restrict__ ce2,
    const bf16_t* __restrict__ msg,
    float* __restrict__ s_acc, int* __restrict__ woff,
    bf16_t* __restrict__ buf, int use_csr)
{
    __shared__ bf16_t wf[8192];      // eW1f, eW2f (16 KB)
    __shared__ bf16_t hf[4][1024];   // hidden frags, then msg tile (time-multiplexed)

    const int tid  = threadIdx.x;
    const int wave = tid >> 6;
    const int lane = tid & 63;
    const int quad = lane >> 4;
    const int lrow = lane & 15;

    #pragma unroll
    for (int i = 0; i < 4; ++i) {
        int chunk = tid + i * 256;
        *(bf16x8*)(wf + chunk * 8) = *(const bf16x8*)(wcat + 8192 + chunk * 8);
    }
    __syncthreads();

    const int ebase = blockIdx.x * 64 + wave * 16;
    bf16_t* h = hf[wave];
    const int r0 = lane >> 3;        // rows 0..7 / 8..15 for msg gather
    const int c0 = lane & 7;         // 16B chunk within a row
    const int r1 = 8 + r0;
    // swizzled LDS element offsets for the two 16B chunks this lane moves
    const int b0 = r0 * 64 + ((c0 * 8) ^ (((r0 >> 2) & 3) << 4));
    const int b1 = r1 * 64 + ((c0 * 8) ^ (((r1 >> 2) & 3) << 4));

    // issue msg-row gathers (coalesced 16B, 8 lanes per row) + CSR pos atomics early
    int dA = dst[ebase + r0];
    int dB = dst[ebase + r1];
    bf16x8 mA = *(const bf16x8*)(msg + (size_t)dA * 64 + c0 * 8);
    bf16x8 mB = *(const bf16x8*)(msg + (size_t)dB * 64 + c0 * 8);
    int pe_l = 0;
    if (use_csr && lane < 16) pe_l = atomicAdd(&woff[src[ebase + lane]], 1);

    // er MLP layer 1 (hides gather latency under edge_feats loads + MFMA)
    f32x4 acc[4];
    {
        const float* efr = edge_feats + (size_t)(ebase + lrow) * 64;
        bf16x8 h0_, l0_, h1_, l1_;
        mk_frag_hilo(efr, quad, h0_, l0_, h1_, l1_);
        gemm64_hilo(wf, 0, h0_, l0_, h1_, l1_, acc, lane);
        epi_to_frag(acc, ce1, h, lrow, quad);
    }
    // pull hidden A-frags into registers, then retire hf -> msg tile
    bf16x8 a0 = *(const bf16x8*)(h + lane * 8);
    bf16x8 a1 = *(const bf16x8*)(h + (lane + 64) * 8);
    __builtin_amdgcn_wave_barrier();
    *(bf16x8*)(h + b0) = mA;
    *(bf16x8*)(h + b1) = mB;
    __builtin_amdgcn_wave_barrier();

    // er MLP layer 2 (register A-operands; wf B-operands)
    gemm64(wf, 1, a0, a1, acc, lane);
    __builtin_amdgcn_wave_barrier();

    if (use_csr) {
        // gate in place: cell (e=quad*4+r, col=nt*16+lrow)
        #pragma unroll
        for (int nt = 0; nt < 4; ++nt) {
            float bb = ce2[nt * 16 + lrow];
            #pragma unroll
            for (int r = 0; r < 4; ++r) {
                int e = quad * 4 + r;
                int ci = e * 64 + ((nt * 16 + lrow) ^ (((e >> 2) & 3) << 4));
                float er = gelu_f(acc[nt][r] + bb);
                h[ci] = (bf16_t)(er * (float)h[ci]);
            }
        }
        __builtin_amdgcn_wave_barrier();
        // scatter full 128B rows: 8 lanes x 16B contiguous per edge row
        int peA = __shfl(pe_l, r0);
        int peB = __shfl(pe_l, r1);
        bf16x8 gA = *(const bf16x8*)(h + b0);
        bf16x8 gB = *(const bf16x8*)(h + b1);
        *(bf16x8*)(buf + (size_t)peA * 64 + c0 * 8) = gA;
        *(bf16x8*)(buf + (size_t)peB * 64 + c0 * 8) = gB;
    } else {
        #pragma unroll
        for (int nt = 0; nt < 4; ++nt) {
            float bb = ce2[nt * 16 + lrow];
            #pragma unroll
            for (int r = 0; r < 4; ++r) {
                int e = quad * 4 + r;
                int ci = e * 64 + ((nt * 16 + lrow) ^ (((e >> 2) & 3) << 4));
                float er = gelu_f(acc[nt][r] + bb);
                unsafeAtomicAdd(&s_acc[(size_t)src[ebase + e] * 64 + nt * 16 + lrow],
                                er * (float)h[ci]);
            }
        }
    }
}

// ---------------- aggregation: contiguous CSR segments, vectorized 16B loads ----------------
// lane = rg*8 + cc: row-group rg (0..7) x col-chunk cc (0..7, 8 bf16 each).
// 1 KB per wave-load; butterfly shfl_xor reduces the 8 row-groups.
__global__ __launch_bounds__(256) void agg_kernel(
    const bf16_t* __restrict__ buf, const int* __restrict__ woff,
    const int* __restrict__ cnt, float* __restrict__ agg)
{
    const int wave = threadIdx.x >> 6;
    const int lane = threadIdx.x & 63;
    const int n = blockIdx.x * 4 + wave;
    const int deg = cnt[n];
    const int end = woff[n];            // after edge_kernel atomics, woff = start + cnt
    const int start = end - deg;
    const int rg = lane >> 3;
    const int cc = lane & 7;

    float a[8] = {0.f, 0.f, 0.f, 0.f, 0.f, 0.f, 0.f, 0.f};
    for (int b = start; b < end; b += 8) {
        int row = b + rg;
        if (row < end) {
            bf16x8 v = *(const bf16x8*)(buf + (size_t)row * 64 + cc * 8);
            #pragma unroll
            for (int j = 0; j < 8; ++j) a[j] += (float)v[j];
        }
    }
    #pragma unroll
    for (int off = 8; off < 64; off <<= 1) {
        #pragma unroll
        for (int j = 0; j < 8; ++j) a[j] += __shfl_xor(a[j], off);
    }
    if (lane < 8) {
        float invd = (deg > 0) ? __builtin_amdgcn_rcpf((float)deg) : 0.f;
        float* dstp = agg + (size_t)n * 64 + cc * 8;
        #pragma unroll
        for (int j = 0; j < 8; ++j) dstp[j] = a[j] * invd;
    }
}

// ---------------- update MLP ----------------
__global__ __launch_bounds__(256) void update_kernel(
    const float* __restrict__ node_feats,
    const float* __restrict__ aggv, const int* __restrict__ cnt,   // cnt!=null -> divide
    const bf16_t* __restrict__ uW1f, const float* __restrict__ cu1,
    const bf16_t* __restrict__ uW2f, const float* __restrict__ cu2,
    float* __restrict__ out)
{
    __shared__ bf16_t w1f[8192];
    __shared__ bf16_t w2f[4096];
    __shared__ bf16_t hf[4][1024];

    const int tid  = threadIdx.x;
    const int wave = tid >> 6;
    const int lane = tid & 63;
    const int quad = lane >> 4;
    const int lrow = lane & 15;

    #pragma unroll
    for (int i = 0; i < 4; ++i) {
        int chunk = tid + i * 256;
        *(bf16x8*)(w1f + chunk * 8) = *(const bf16x8*)(uW1f + chunk * 8);
    }
    #pragma unroll
    for (int i = 0; i < 2; ++i) {
        int chunk = tid + i * 256;
        *(bf16x8*)(w2f + chunk * 8) = *(const bf16x8*)(uW2f + chunk * 8);
    }
    __syncthreads();

    const int nbase = blockIdx.x * 64 + wave * 16;
    int arow = nbase + lrow;
    arow = arow < NN ? arow : NN - 1;

    const float* nf   = node_feats + (size_t)arow * 64;
    const float* srow = aggv + (size_t)arow * 64;
    float inv = cnt ? 1.0f / fmaxf((float)cnt[arow], 1.0f) : 1.0f;

    bf16x8 ah[4], al[4];
    #pragma unroll
    for (int j = 0; j < 8; ++j) {
        float x0 = nf[quad * 8 + j];
        float x1 = nf[32 + quad * 8 + j];
        float x2 = srow[quad * 8 + j] * inv;
        float x3 = srow[32 + quad * 8 + j] * inv;
        bf16_t h0 = (bf16_t)x0, h1 = (bf16_t)x1, h2 = (bf16_t)x2, h3 = (bf16_t)x3;
        ah[0][j] = h0; al[0][j] = (bf16_t)(x0 - (float)h0);
        ah[1][j] = h1; al[1][j] = (bf16_t)(x1 - (float)h1);
        ah[2][j] = h2; al[2][j] = (bf16_t)(x2 - (float)h2);
        ah[3][j] = h3; al[3][j] = (bf16_t)(x3 - (float)h3);
    }

    f32x4 acc[4];
    #pragma unroll
    for (int nt = 0; nt < 4; ++nt) {
        f32x4 c = {0.f, 0.f, 0.f, 0.f};
        #pragma unroll
        for (int kk = 0; kk < 4; ++kk) {
            bf16x8 b = *(const bf16x8*)(w1f + ((nt * 4 + kk) * 64 + lane) * 8);
            c = __builtin_amdgcn_mfma_f32_16x16x32_bf16(ah[kk], b, c, 0, 0, 0);
            c = __builtin_amdgcn_mfma_f32_16x16x32_bf16(al[kk], b, c, 0, 0, 0);
        }
        acc[nt] = c;
    }
    bf16_t* hb = hf[wave];
    epi_to_frag(acc, cu1, hb, lrow, quad);

    bf16x8 ha0 = *(const bf16x8*)(hb + lane * 8);
    bf16x8 ha1 = *(const bf16x8*)(hb + (lane + 64) * 8);
    gemm64(w2f, 0, ha0, ha1, acc, lane);

    #pragma unroll
    for (int nt = 0; nt < 4; ++nt) {
        int col = nt * 16 + lrow;
        float bb = cu2[col];
        #pragma unroll
        for (int r = 0; r < 4; ++r) {
            int row = nbase + quad * 4 + r;
            if (row < NN)
                out[(size_t)row * 64 + col] = gelu_f(acc[nt][r] + bb);
        }
    }
}

// ---------------- launch ----------------
extern "C" void kernel_launch(void* const* d_in, const int* in_sizes, int n_in,
                              void* d_out, int out_size, void* d_ws, size_t ws_size,
                              hipStream_t stream) {
    const float* node_feats = (const float*)d_in[0];
    const float* edge_feats = (const float*)d_in[1];
    const int*   src        = (const int*)d_in[2];
    const int*   dst        = (const int*)d_in[3];

    char* ws = (char*)d_ws;
    const bool csr = ws_size >= (size_t)116500000;

    size_t off = 0;
    bf16_t* buf = nullptr; float* agg = nullptr; bf16_t* msg = nullptr;
    float* s_acc = nullptr; int* cnt = nullptr; int* woff = nullptr;
    int* part = nullptr; int* btot = nullptr;

    if (csr) {
        buf = (bf16_t*)(ws + off); off += (size_t)NE * 128;    // 102,400,000
        char* aggbase = ws + off;
        agg = (float*)aggbase;     off += (size_t)NN * 256;    //  12,800,000
        msg = (bf16_t*)(aggbase + (size_t)NE * 4);             // alias — dead before agg write
        cnt  = (int*)(ws + off); off += (size_t)NN * 4;
        woff = (int*)(ws + off); off += (size_t)NN * 4;
        part = (int*)(ws + off); off += (size_t)NN * 4;
        btot = (int*)(ws + off); off += 1024;
    } else {
        s_acc = (float*)(ws + off);  off += (size_t)NN * 256;
        cnt   = (int*)(ws + off);    off += (size_t)NN * 4;
        msg   = (bf16_t*)(ws + off); off += (size_t)NN * 128;
    }
    bf16_t* wcat = (bf16_t*)(ws + off); off += 32768;
    bf16_t* uW1f = (bf16_t*)(ws + off); off += 16384;
    bf16_t* uW2f = (bf16_t*)(ws + off); off += 8192;
    float* cm1 = (float*)(ws + off); off += 256;
    float* cm2 = (float*)(ws + off); off += 256;
    float* ce1 = (float*)(ws + off); off += 256;
    float* ce2 = (float*)(ws + off); off += 256;
    float* cu1 = (float*)(ws + off); off += 256;
    float* cu2 = (float*)(ws + off); off += 256;

    if (csr) {
        hipMemsetAsync(cnt, 0, (size_t)NN * 4, stream);
    } else {
        hipMemsetAsync(s_acc, 0, (size_t)NN * 256 + (size_t)NN * 4, stream);
    }

    fold_kernel<<<6, 256, 0, stream>>>(
        (const float*)d_in[4],  (const float*)d_in[5],  (const float*)d_in[6],  (const float*)d_in[7],
        (const float*)d_in[8],  (const float*)d_in[9],
        (const float*)d_in[10], (const float*)d_in[11], (const float*)d_in[12], (const float*)d_in[13],
        (const float*)d_in[14], (const float*)d_in[15],
        (const float*)d_in[16], (const float*)d_in[17], (const float*)d_in[18], (const float*)d_in[19],
        (const float*)d_in[20], (const float*)d_in[21], (const float*)d_in[22], (const float*)d_in[23],
        (const float*)d_in[24], (const float*)d_in[25],
        (const float*)d_in[26], (const float*)d_in[27], (const float*)d_in[28], (const float*)d_in[29],
        (const float*)d_in[30], (const float*)d_in[31],
        wcat, uW1f, uW2f, cm1, cm2, ce1, ce2, cu1, cu2);

    node_msg_kernel<<<(NN + 63) / 64, 256, 0, stream>>>(node_feats, wcat, cm1, cm2, msg);

    hist_kernel<<<(NE + 255) / 256, 256, 0, stream>>>(src, cnt);

    if (csr) {
        const int NBLK = (NN + 255) / 256;   // 196
        scanA_kernel<<<NBLK, 256, 0, stream>>>(cnt, part, btot);
        scanB_kernel<<<1, 256, 0, stream>>>(btot, NBLK);
        scanC_kernel<<<NBLK, 256, 0, stream>>>(part, btot, woff);
    }

    edge_kernel<<<NE / 64, 256, 0, stream>>>(
        edge_feats, src, dst, wcat, ce1, ce2, msg, s_acc, woff, buf, csr ? 1 : 0);

    if (csr) {
        agg_kernel<<<NN / 4, 256, 0, stream>>>(buf, woff, cnt, agg);
        update_kernel<<<(NN + 63) / 64, 256, 0, stream>>>(
            node_feats, agg, nullptr, uW1f, cu1, uW2f, cu2, (float*)d_out);
    } else {
        update_kernel<<<(NN + 63) / 64, 256, 0, stream>>>(
            node_feats, s_acc, cnt, uW1f, cu1, uW2f, cu2, (float*)d_out);
    }
}